// Round 4
// baseline (556.990 us; speedup 1.0000x reference)
//
#include <hip/hip_runtime.h>

// Problem constants (fixed by the reference)
#define Bb  2
#define Ss  2048
#define Dd  2048
#define HKV 8
#define QPK 4
#define HD  64
#define MR  (Bb * Ss)   // 4096 token rows
#define NQ  2048        // HQ*HD
#define NKV 512         // HKV*HD

#define LOG2E 1.4426950408889634f

typedef unsigned short u16;
typedef __attribute__((ext_vector_type(8))) short s16x8;   // 8 x bf16 (4 VGPRs)
typedef __attribute__((ext_vector_type(4))) float f32x4;   // MFMA accumulator

__device__ __forceinline__ u16 f2bf(float f) {
  unsigned u = __float_as_uint(f);
  u += 0x7fffu + ((u >> 16) & 1u);   // RNE; inputs finite
  return (u16)(u >> 16);
}

// ---------------------------------------------------------------------------
// LayerNorm: one block per row, fp32 in -> bf16 out
// ---------------------------------------------------------------------------
__global__ __launch_bounds__(256) void ln_kernel(
    const float* __restrict__ x, const float* __restrict__ g,
    const float* __restrict__ be, u16* __restrict__ xn)
{
  int row = blockIdx.x;
  int tid = threadIdx.x;
  const float4* xr = (const float4*)(x + (size_t)row * Dd);
  float4 a = xr[tid];
  float4 b4 = xr[tid + 256];
  float s  = a.x + a.y + a.z + a.w + b4.x + b4.y + b4.z + b4.w;
  float ss = a.x*a.x + a.y*a.y + a.z*a.z + a.w*a.w
           + b4.x*b4.x + b4.y*b4.y + b4.z*b4.z + b4.w*b4.w;
  #pragma unroll
  for (int off = 32; off > 0; off >>= 1) {
    s  += __shfl_down(s, off);
    ss += __shfl_down(ss, off);
  }
  __shared__ float red[8];
  int lane = tid & 63, w = tid >> 6;
  if (lane == 0) { red[w] = s; red[4 + w] = ss; }
  __syncthreads();
  s  = red[0] + red[1] + red[2] + red[3];
  ss = red[4] + red[5] + red[6] + red[7];
  float mu = s * (1.0f / Dd);
  float rs = rsqrtf(ss * (1.0f / Dd) - mu * mu + 1e-5f);

  u16* xo = xn + (size_t)row * Dd;
  const float4* gv4 = (const float4*)g;
  const float4* bv4 = (const float4*)be;
  #pragma unroll
  for (int p = 0; p < 2; ++p) {
    int idx = tid + p * 256;
    float4 xv = (p == 0) ? a : b4;
    float4 gg = gv4[idx], bb = bv4[idx];
    ushort4 pk;
    pk.x = f2bf((xv.x - mu) * rs * gg.x + bb.x);
    pk.y = f2bf((xv.y - mu) * rs * gg.y + bb.y);
    pk.z = f2bf((xv.z - mu) * rs * gg.z + bb.z);
    pk.w = f2bf((xv.w - mu) * rs * gg.w + bb.w);
    *(ushort4*)(xo + idx * 4) = pk;
  }
}

// ---------------------------------------------------------------------------
// Weight transpose + cast: W (K x N) fp32 -> WT (N x K) bf16
// ---------------------------------------------------------------------------
__global__ __launch_bounds__(256) void transpose_cast(
    const float* __restrict__ W, u16* __restrict__ WT, int K, int N)
{
  __shared__ float tile[32][33];
  int tx = threadIdx.x & 31, ty = threadIdx.x >> 5;  // ty 0..7
  int n0 = blockIdx.x * 32, k0 = blockIdx.y * 32;
  #pragma unroll
  for (int i = 0; i < 4; ++i)
    tile[ty + 8 * i][tx] = W[(size_t)(k0 + ty + 8 * i) * N + n0 + tx];
  __syncthreads();
  #pragma unroll
  for (int i = 0; i < 4; ++i)
    WT[(size_t)(n0 + ty + 8 * i) * K + k0 + tx] = f2bf(tile[tx][ty + 8 * i]);
}

// ---------------------------------------------------------------------------
// V transpose: vb (b,t, h*64+d) bf16 -> vT (b*512 + h*64+d, t) bf16
// ---------------------------------------------------------------------------
__global__ __launch_bounds__(256) void transpose_v(
    const u16* __restrict__ vb, u16* __restrict__ vT)
{
  __shared__ u16 tile[32][33];
  int tx = threadIdx.x & 31, ty = threadIdx.x >> 5;
  int c0 = blockIdx.x * 32;     // 0..511  (h*64+d)
  int r0 = blockIdx.y * 32;     // 0..4095 (b*2048+t), tiles never cross b
  #pragma unroll
  for (int i = 0; i < 4; ++i)
    tile[ty + 8 * i][tx] = vb[(size_t)(r0 + ty + 8 * i) * NKV + c0 + tx];
  __syncthreads();
  int b = r0 >> 11, t = r0 & 2047;
  #pragma unroll
  for (int i = 0; i < 4; ++i)
    vT[((size_t)(b * NKV + c0 + ty + 8 * i)) * Ss + t + tx] = tile[tx][ty + 8 * i];
}

// ---------------------------------------------------------------------------
// bf16 MFMA GEMM: C(M,N) = (A(M,K)bf16 @ BT(N,K)^T + bias) * scale
// 128x128 tile, BK=32; output fp32 or bf16
// ---------------------------------------------------------------------------
template<bool BF16OUT>
__global__ __launch_bounds__(256) void gemm_bt(
    const u16* __restrict__ A, const u16* __restrict__ BT,
    const float* __restrict__ bias, void* __restrict__ Cv,
    int M, int N, int K, float scale)
{
  __shared__ u16 As[128][40];
  __shared__ u16 Bs[128][40];
  int tid  = threadIdx.x;
  int lane = tid & 63, wave = tid >> 6;
  int wm = (wave >> 1) * 64, wn = (wave & 1) * 64;
  int m16 = lane & 15, quad = lane >> 4;
  int ar = tid >> 2;
  int ac = (tid & 3) * 8;
  const u16* Ag = A  + (size_t)(blockIdx.y * 128 + ar) * K + ac;
  const u16* Bg = BT + (size_t)(blockIdx.x * 128 + ar) * K + ac;

  f32x4 acc[4][4] = {};
  for (int k0 = 0; k0 < K; k0 += 32) {
    int4 a0 = *(const int4*)(Ag + k0);
    int4 a1 = *(const int4*)(Ag + (size_t)64 * K + k0);
    int4 b0 = *(const int4*)(Bg + k0);
    int4 b1 = *(const int4*)(Bg + (size_t)64 * K + k0);
    __syncthreads();
    *(int4*)&As[ar][ac]      = a0;
    *(int4*)&As[ar + 64][ac] = a1;
    *(int4*)&Bs[ar][ac]      = b0;
    *(int4*)&Bs[ar + 64][ac] = b1;
    __syncthreads();
    s16x8 af[4], bf[4];
    #pragma unroll
    for (int i = 0; i < 4; ++i)
      af[i] = *(const s16x8*)&As[wm + i * 16 + m16][quad * 8];
    #pragma unroll
    for (int j = 0; j < 4; ++j)
      bf[j] = *(const s16x8*)&Bs[wn + j * 16 + m16][quad * 8];
    #pragma unroll
    for (int i = 0; i < 4; ++i)
      #pragma unroll
      for (int j = 0; j < 4; ++j)
        acc[i][j] = __builtin_amdgcn_mfma_f32_16x16x32_bf16(af[i], bf[j], acc[i][j], 0, 0, 0);
  }
  #pragma unroll
  for (int i = 0; i < 4; ++i) {
    #pragma unroll
    for (int j = 0; j < 4; ++j) {
      int col = blockIdx.x * 128 + wn + j * 16 + m16;
      float bcol = bias[col];
      #pragma unroll
      for (int r = 0; r < 4; ++r) {
        int rowg = blockIdx.y * 128 + wm + i * 16 + quad * 4 + r;
        float val = (acc[i][j][r] + bcol) * scale;
        if constexpr (BF16OUT)
          ((u16*)Cv)[(size_t)rowg * N + col] = f2bf(val);
        else
          ((float*)Cv)[(size_t)rowg * N + col] = val;
      }
    }
  }
}

// ---------------------------------------------------------------------------
// Pass A: per-column sum of exp2 over the QUERY axis (base-2 domain).
// One wave per (bh, qk, T-tile of 64).  K B-frags preloaded in registers;
// Q A-frags loaded directly from global (L2) each t-block of 64.
// No running max (scores bounded): l = sum exp2(s - 24); c = 24 + log2(l).
// Grid id: bh in low 4 bits -> XCD (id%8) sees 2 bh => K/V/Q L2-resident.
// ---------------------------------------------------------------------------
__global__ __launch_bounds__(64, 2) void pass_a_mfma(
    const u16* __restrict__ qb, const u16* __restrict__ kb,
    float* __restrict__ cst)
{
  int id = blockIdx.x;
  int bh = id & 15, rest = id >> 4;
  int qk = rest >> 5, Tt = rest & 31;       // Tt ascending: longest first
  int b = bh >> 3, h = bh & 7;
  int lane = threadIdx.x;
  int m16 = lane & 15, quad = lane >> 4;
  int T0 = Tt * 64;

  const u16* kbase = kb + (size_t)b * Ss * NKV + h * HD;
  const u16* qbase = qb + (size_t)b * Ss * NQ + (h * QPK + qk) * HD;

  s16x8 kf[4][2];   // B-operand frags (n=T), loaded once
  #pragma unroll
  for (int j = 0; j < 4; ++j) {
    const u16* kp = kbase + (size_t)(T0 + j * 16 + m16) * NKV + quad * 8;
    kf[j][0] = *(const s16x8*)kp;
    kf[j][1] = *(const s16x8*)(kp + 32);
  }

  float ls[4] = {0.f, 0.f, 0.f, 0.f};

  for (int t0 = T0; t0 < Ss; t0 += 64) {
    s16x8 af[4][2];
    #pragma unroll
    for (int i = 0; i < 4; ++i) {
      const u16* qp = qbase + (size_t)(t0 + i * 16 + m16) * NQ + quad * 8;
      af[i][0] = *(const s16x8*)qp;
      af[i][1] = *(const s16x8*)(qp + 32);
    }
    bool diag = (t0 == T0);
    #pragma unroll
    for (int j = 0; j < 4; ++j) {
      f32x4 a4[4];
      #pragma unroll
      for (int i = 0; i < 4; ++i) {
        f32x4 z = {};
        z = __builtin_amdgcn_mfma_f32_16x16x32_bf16(af[i][0], kf[j][0], z, 0, 0, 0);
        a4[i] = __builtin_amdgcn_mfma_f32_16x16x32_bf16(af[i][1], kf[j][1], z, 0, 0, 0);
      }
      float l = ls[j];
      #pragma unroll
      for (int i = 0; i < 4; ++i) {
        int tg = t0 + i * 16 + quad * 4;
        int Tg = T0 + j * 16 + m16;
        #pragma unroll
        for (int r = 0; r < 4; ++r) {
          float zz = a4[i][r];
          if (diag && (tg + r < Tg)) zz = -200.0f;   // exp2 -> 0
          l += exp2f(zz - 24.0f);
        }
      }
      ls[j] = l;
    }
  }
  // quads hold disjoint t-subsets of the same columns: plain sum merge
  #pragma unroll
  for (int j = 0; j < 4; ++j) {
    float l = ls[j];
    l += __shfl_xor(l, 16);
    l += __shfl_xor(l, 32);
    if (quad == 0)
      cst[(size_t)(bh * QPK + qk) * Ss + T0 + j * 16 + m16] = 24.0f + __log2f(l);
  }
}

// ---------------------------------------------------------------------------
// Pass B: out[t,:] = sum_{T<=t} exp2(s2(t,T)-c[T]) * v[T,:]
// One wave per (bh, qk, t-tile of 64).  Q B-frags preloaded; K/V frags
// direct from global (L2).  P (64t x 64T bf16) round-trips through LDS
// (stride 72 u16: 16B-aligned rows, 2-way banks on b128 reads = free).
// Longest t-tiles dispatch first.
// ---------------------------------------------------------------------------
__global__ __launch_bounds__(64, 2) void pass_b_mfma(
    const u16* __restrict__ qb, const u16* __restrict__ kb,
    const u16* __restrict__ vT, const float* __restrict__ cst,
    u16* __restrict__ attn)
{
  __shared__ u16 P[64][72];   // 9216 B per 1-wave block
  int id = blockIdx.x;
  int bh = id & 15, rest = id >> 4;
  int qk = rest >> 5, tt = 31 - (rest & 31);   // longest first
  int b = bh >> 3, h = bh & 7;
  int lane = threadIdx.x;
  int m16 = lane & 15, quad = lane >> 4;
  int t0w = tt * 64;

  const u16* qbase = qb + (size_t)b * Ss * NQ + (h * QPK + qk) * HD;
  const u16* kbase = kb + (size_t)b * Ss * NKV + h * HD;
  const u16* vbase = vT + (size_t)(bh * 64) * Ss;
  const float* cbase = cst + (size_t)(bh * QPK + qk) * Ss;

  s16x8 qf[4][2];   // B-operand (n=t) frags for the wave's 64 t-rows
  #pragma unroll
  for (int tj = 0; tj < 4; ++tj) {
    const u16* qp = qbase + (size_t)(t0w + tj * 16 + m16) * NQ + quad * 8;
    qf[tj][0] = *(const s16x8*)qp;
    qf[tj][1] = *(const s16x8*)(qp + 32);
  }

  f32x4 oacc[4][4] = {};   // [t-tile][d-tile]: row t = quad*4+r, col d = m16

  for (int T0 = 0; T0 <= t0w; T0 += 64) {
    bool diag = (T0 == t0w);
    // ---- scores S^T (m=T, n=t) -> normalized bf16 P in LDS ----
    #pragma unroll
    for (int i = 0; i < 4; ++i) {
      const u16* kp = kbase + (size_t)(T0 + i * 16 + m16) * NKV + quad * 8;
      s16x8 k0 = *(const s16x8*)kp;
      s16x8 k1 = *(const s16x8*)(kp + 32);
      float4 cc = *(const float4*)(cbase + T0 + i * 16 + quad * 4);
      int Tg = T0 + i * 16 + quad * 4;
      #pragma unroll
      for (int tj = 0; tj < 4; ++tj) {
        f32x4 z = {};
        z = __builtin_amdgcn_mfma_f32_16x16x32_bf16(k0, qf[tj][0], z, 0, 0, 0);
        z = __builtin_amdgcn_mfma_f32_16x16x32_bf16(k1, qf[tj][1], z, 0, 0, 0);
        int t = t0w + tj * 16 + m16;
        float w0 = exp2f(z[0] - cc.x);
        float w1 = exp2f(z[1] - cc.y);
        float w2 = exp2f(z[2] - cc.z);
        float w3 = exp2f(z[3] - cc.w);
        if (diag) {
          if (Tg + 0 > t) w0 = 0.f;
          if (Tg + 1 > t) w1 = 0.f;
          if (Tg + 2 > t) w2 = 0.f;
          if (Tg + 3 > t) w3 = 0.f;
        }
        unsigned u0 = __float_as_uint(w0) + 0x8000u;
        unsigned u1 = __float_as_uint(w1) + 0x8000u;
        unsigned u2 = __float_as_uint(w2) + 0x8000u;
        unsigned u3 = __float_as_uint(w3) + 0x8000u;
        uint2 pk;
        pk.x = (u0 >> 16) | (u1 & 0xffff0000u);
        pk.y = (u2 >> 16) | (u3 & 0xffff0000u);
        *(uint2*)&P[tj * 16 + m16][i * 16 + quad * 4] = pk;
      }
    }
    // ---- PV: oacc += P(t,T) @ V^T(d,T) ----  (same wave: lgkm wait only)
    #pragma unroll
    for (int kh = 0; kh < 2; ++kh) {
      s16x8 pa[4], vf[4];
      #pragma unroll
      for (int ti = 0; ti < 4; ++ti)
        pa[ti] = *(const s16x8*)&P[ti * 16 + m16][kh * 32 + quad * 8];
      #pragma unroll
      for (int dj = 0; dj < 4; ++dj)
        vf[dj] = *(const s16x8*)(vbase + (size_t)(dj * 16 + m16) * Ss + T0 + kh * 32 + quad * 8);
      #pragma unroll
      for (int ti = 0; ti < 4; ++ti)
        #pragma unroll
        for (int dj = 0; dj < 4; ++dj)
          oacc[ti][dj] = __builtin_amdgcn_mfma_f32_16x16x32_bf16(pa[ti], vf[dj], oacc[ti][dj], 0, 0, 0);
    }
  }
  // ---- epilogue: attn (b, t, (h*QPK+qk)*64 + d) bf16 ----
  u16* abase = attn + (size_t)b * Ss * NQ + (h * QPK + qk) * HD;
  #pragma unroll
  for (int ti = 0; ti < 4; ++ti)
    #pragma unroll
    for (int dj = 0; dj < 4; ++dj)
      #pragma unroll
      for (int r = 0; r < 4; ++r)
        abase[(size_t)(t0w + ti * 16 + quad * 4 + r) * NQ + dj * 16 + m16] = f2bf(oacc[ti][dj][r]);
}

// ---------------------------------------------------------------------------
extern "C" void kernel_launch(void* const* d_in, const int* in_sizes, int n_in,
                              void* d_out, int out_size, void* d_ws, size_t ws_size,
                              hipStream_t stream)
{
  (void)in_sizes; (void)n_in; (void)out_size; (void)ws_size;
  const float* x   = (const float*)d_in[0];
  const float* lng = (const float*)d_in[1];
  const float* lnb = (const float*)d_in[2];
  const float* Wq  = (const float*)d_in[3];
  const float* bq  = (const float*)d_in[4];
  const float* Wk  = (const float*)d_in[5];
  const float* bk  = (const float*)d_in[6];
  const float* Wv  = (const float*)d_in[7];
  const float* bv  = (const float*)d_in[8];
  const float* Wo  = (const float*)d_in[9];
  const float* bo  = (const float*)d_in[10];
  float* out = (float*)d_out;

  char* ws = (char*)d_ws;
  size_t off = 0;
  auto take = [&](size_t bytes) -> char* {
    char* p = ws + off;
    off += (bytes + 255) & ~(size_t)255;
    return p;
  };
  u16*    xnb   = (u16*)take((size_t)MR * Dd * 2);           // 16 MB
  u16*    wqT   = (u16*)take((size_t)NQ * Dd * 2);           // 8 MB
  u16*    wkT   = (u16*)take((size_t)NKV * Dd * 2);          // 2 MB
  u16*    wvT   = (u16*)take((size_t)NKV * Dd * 2);          // 2 MB
  u16*    woT   = (u16*)take((size_t)Dd * NQ * 2);           // 8 MB
  u16*    qbB   = (u16*)take((size_t)MR * NQ * 2);           // 16 MB
  u16*    kbB   = (u16*)take((size_t)MR * NKV * 2);          // 4 MB
  u16*    vbB   = (u16*)take((size_t)MR * NKV * 2);          // 4 MB
  u16*    vTb   = (u16*)take((size_t)MR * NKV * 2);          // 4 MB
  float*  cst   = (float*)take((size_t)Bb * HKV * QPK * Ss * 4); // 0.5 MB
  u16*    attnb = (u16*)take((size_t)MR * NQ * 2);           // 16 MB

  ln_kernel<<<MR, 256, 0, stream>>>(x, lng, lnb, xnb);
  transpose_cast<<<dim3(NQ / 32, Dd / 32), 256, 0, stream>>>(Wq, wqT, Dd, NQ);
  transpose_cast<<<dim3(NKV / 32, Dd / 32), 256, 0, stream>>>(Wk, wkT, Dd, NKV);
  transpose_cast<<<dim3(NKV / 32, Dd / 32), 256, 0, stream>>>(Wv, wvT, Dd, NKV);
  transpose_cast<<<dim3(NQ / 32, Dd / 32), 256, 0, stream>>>(Wo, woT, Dd, NQ);

  // q pre-scaled by 1/sqrt(HD) * log2(e): scores land in base-2 domain
  gemm_bt<true><<<dim3(NQ / 128, MR / 128), 256, 0, stream>>>(xnb, wqT, bq, qbB, MR, NQ, Dd, 0.125f * LOG2E);
  gemm_bt<true><<<dim3(NKV / 128, MR / 128), 256, 0, stream>>>(xnb, wkT, bk, kbB, MR, NKV, Dd, 1.0f);
  gemm_bt<true><<<dim3(NKV / 128, MR / 128), 256, 0, stream>>>(xnb, wvT, bv, vbB, MR, NKV, Dd, 1.0f);
  transpose_v<<<dim3(NKV / 32, MR / 32), 256, 0, stream>>>(vbB, vTb);

  pass_a_mfma<<<2048, 64, 0, stream>>>(qbB, kbB, cst);
  pass_b_mfma<<<2048, 64, 0, stream>>>(qbB, kbB, vTb, cst, attnb);

  gemm_bt<false><<<dim3(Dd / 128, MR / 128), 256, 0, stream>>>(attnb, woT, bo, out, MR, Dd, NQ, 1.0f);
}